// Round 2
// baseline (847.441 us; speedup 1.0000x reference)
//
#include <hip/hip_runtime.h>

#define HIDD 2048
#define SEQ  2048
#define BATCH 4
#define NHQ  16
#define NKVH 4
#define HDIM 128

typedef unsigned short u16;
typedef unsigned int   u32;
using bf16x8 = __attribute__((ext_vector_type(8))) __bf16;
using u16x8  = __attribute__((ext_vector_type(8))) u16;
using u16x4  = __attribute__((ext_vector_type(4))) u16;
using f32x4  = __attribute__((ext_vector_type(4))) float;

__device__ __forceinline__ float bf2f(u16 v){ u32 u = ((u32)v) << 16; float f; __builtin_memcpy(&f, &u, 4); return f; }
__device__ __forceinline__ u16 f2bf(float f){ u32 u; __builtin_memcpy(&u, &f, 4); u += 0x7fffu + ((u >> 16) & 1u); return (u16)(u >> 16); }

__device__ __forceinline__ void gl_lds16(const void* g, void* l){
  __builtin_amdgcn_global_load_lds((const __attribute__((address_space(1))) void*)g,
                                   (__attribute__((address_space(3))) void*)l, 16, 0, 0);
}

// ---------------- prep kernels ----------------

__global__ void cvt_f32_bf16(const float* __restrict__ in, u16* __restrict__ out, int n4){
  int i = blockIdx.x * 256 + threadIdx.x;
  if (i >= n4) return;
  float4 v = ((const float4*)in)[i];
  u16x4 o; o[0] = f2bf(v.x); o[1] = f2bf(v.y); o[2] = f2bf(v.z); o[3] = f2bf(v.w);
  ((u16x4*)out)[i] = o;
}

// in: f32 [R][C] -> out: bf16 [C][R]
__global__ void transpose_cvt_f32(const float* __restrict__ in, u16* __restrict__ out, int R, int C){
  __shared__ float t[32][33];
  int c0 = blockIdx.x * 32, r0 = blockIdx.y * 32;
  int tx = threadIdx.x, ty = threadIdx.y;
  #pragma unroll
  for (int i = 0; i < 4; i++)
    t[ty + 8*i][tx] = in[(size_t)(r0 + ty + 8*i) * C + c0 + tx];
  __syncthreads();
  #pragma unroll
  for (int i = 0; i < 4; i++)
    out[(size_t)(c0 + ty + 8*i) * R + r0 + tx] = f2bf(t[tx][ty + 8*i]);
}

// V [B*S][NKV*HD] bf16 -> Vt [B][NKV][HD][S] bf16
__global__ void transpose_v(const u16* __restrict__ V, u16* __restrict__ Vt){
  __shared__ u16 t[32][33];
  int bg = blockIdx.z;
  int b = bg >> 2, g = bg & 3;
  const u16* in = V + (size_t)b * SEQ * (NKVH*HDIM) + g * HDIM;
  u16* out = Vt + (size_t)bg * HDIM * SEQ;
  int c0 = blockIdx.x * 32, r0 = blockIdx.y * 32;   // c: d (0..127), r: s
  int tx = threadIdx.x, ty = threadIdx.y;
  #pragma unroll
  for (int i = 0; i < 4; i++)
    t[ty + 8*i][tx] = in[(size_t)(r0 + ty + 8*i) * (NKVH*HDIM) + c0 + tx];
  __syncthreads();
  #pragma unroll
  for (int i = 0; i < 4; i++)
    out[(size_t)(c0 + ty + 8*i) * SEQ + r0 + tx] = t[tx][ty + 8*i];
}

// in-place RoPE on bf16 [B*S][ncol]; cos/sin are f32 [S][HD]; scale folded (1/sqrt(HD) for Q)
__global__ void rope_kernel(u16* __restrict__ X, const float* __restrict__ ct, const float* __restrict__ st,
                            int ncol, float scale, int n8){
  int i = blockIdx.x * 256 + threadIdx.x;
  if (i >= n8) return;
  int e0 = i * 8;
  int row = e0 / ncol;                 // ncol is a power of two
  int col = e0 - row * ncol;
  int pos = row & (SEQ - 1);
  int dd  = col & (HDIM - 1);
  u16x8 v = *(const u16x8*)&X[e0];
  const float* cp = ct + (size_t)pos * HDIM + dd;
  const float* sp = st + (size_t)pos * HDIM + dd;
  float f[8];
  #pragma unroll
  for (int j = 0; j < 8; j++) f[j] = bf2f(v[j]);
  u16x8 o;
  #pragma unroll
  for (int j = 0; j < 8; j += 2){
    float c = cp[j], s = sp[j];        // cos/sin repeated in pairs
    float e = f[j], od = f[j+1];
    o[j]   = f2bf((e * c - od * s) * scale);
    o[j+1] = f2bf((od * c + e * s) * scale);
  }
  *(u16x8*)&X[e0] = o;
}

// ---------------- GEMM: C[M][N] = A[M][K] * Bt[N][K]^T (bf16 in, f32 acc) ----------------
// m97 structure: 128x128 tile, BK=32, 4 waves (2x2 of 64x64), global_load_lds width 16,
// (row&3) XOR swizzle on the 32-elem K rows to cut LDS read conflicts 8-way -> 4-way.
template<int OUT_BF16>
__global__ __launch_bounds__(256) void gemm_bt(const u16* __restrict__ A, const u16* __restrict__ Bt,
                                               void* __restrict__ Cv, int M, int N, int K){
  __shared__ __align__(16) u16 As[128*32];
  __shared__ __align__(16) u16 Bs[128*32];
  const int tid = threadIdx.x;
  const int wid = tid >> 6, lane = tid & 63;
  const int lr = lane & 15, lk = lane >> 4;
  const int m0 = blockIdx.y * 128, n0 = blockIdx.x * 128;
  const int wr = (wid >> 1) * 64, wc = (wid & 1) * 64;

  f32x4 acc[4][4];
  #pragma unroll
  for (int m = 0; m < 4; m++)
    #pragma unroll
    for (int n = 0; n < 4; n++) acc[m][n] = f32x4{0.f,0.f,0.f,0.f};

  // staging: wave wid owns chunks {wid*2, wid*2+1} of each 8KB tile (1KB per chunk = 16 rows)
  const int srow = lane >> 2;                                   // 0..15 row within 16-row chunk
  const int swz  = ((lane & 3) * 8) ^ ((srow & 3) * 8);         // swizzled k-offset (elems)
  const u16* Ag = A  + (size_t)(m0 + wid*32 + srow) * K + swz;
  const u16* Bg = Bt + (size_t)(n0 + wid*32 + srow) * K + swz;
  u16* Asl = As + wid * 1024;
  u16* Bsl = Bs + wid * 1024;
  const int rsw = (lr & 3) * 8;                                 // read-side swizzle

  for (int k0 = 0; k0 < K; k0 += 32){
    gl_lds16(Ag + k0,          Asl);
    gl_lds16(Ag + k0 + 16*K,   Asl + 512);
    gl_lds16(Bg + k0,          Bsl);
    gl_lds16(Bg + k0 + 16*K,   Bsl + 512);
    __syncthreads();
    bf16x8 a[4], b[4];
    #pragma unroll
    for (int m = 0; m < 4; m++) a[m] = *(const bf16x8*)&As[(wr + m*16 + lr)*32 + ((lk*8) ^ rsw)];
    #pragma unroll
    for (int n = 0; n < 4; n++) b[n] = *(const bf16x8*)&Bs[(wc + n*16 + lr)*32 + ((lk*8) ^ rsw)];
    #pragma unroll
    for (int m = 0; m < 4; m++)
      #pragma unroll
      for (int n = 0; n < 4; n++)
        acc[m][n] = __builtin_amdgcn_mfma_f32_16x16x32_bf16(a[m], b[n], acc[m][n], 0, 0, 0);
    __syncthreads();
  }
  #pragma unroll
  for (int m = 0; m < 4; m++)
    #pragma unroll
    for (int n = 0; n < 4; n++)
      #pragma unroll
      for (int i = 0; i < 4; i++){
        int gr = m0 + wr + m*16 + lk*4 + i;
        int gc = n0 + wc + n*16 + lr;
        float v = acc[m][n][i];
        if (OUT_BF16) ((u16*)Cv)[(size_t)gr * N + gc] = f2bf(v);
        else          ((float*)Cv)[(size_t)gr * N + gc] = v;
      }
}

// ---------------- flash attention ----------------
// grid: (S/64, NH, B), block 256 (4 waves x 16 q-rows). KV tile 64.
// Q pre-scaled by 1/sqrt(HD) in rope. K staged [64][136] (pad), Vt staged [128][72] (pad).
__global__ __launch_bounds__(256) void attn_kernel(const u16* __restrict__ Q, const u16* __restrict__ Kg,
                                                   const u16* __restrict__ Vt, u16* __restrict__ O){
  const int qt = blockIdx.x, h = blockIdx.y, b = blockIdx.z;
  const int g = h >> 2;
  const int tid = threadIdx.x;
  const int wid = tid >> 6, lane = tid & 63;
  const int lr = lane & 15, lk = lane >> 4;
  const int q0 = qt * 64;

  __shared__ __align__(16) u16 Ks[64*136];
  __shared__ __align__(16) u16 Vs[128*72];
  __shared__ __align__(16) u16 Ps[4][16*72];

  bf16x8 qf[4];
  {
    const int qrow = q0 + wid*16 + lr;
    const u16* qp = Q + (size_t)(b*SEQ + qrow) * (NHQ*HDIM) + h*HDIM + lk*8;
    #pragma unroll
    for (int c = 0; c < 4; c++) qf[c] = *(const bf16x8*)(qp + c*32);
  }

  f32x4 oacc[8];
  #pragma unroll
  for (int f = 0; f < 8; f++) oacc[f] = f32x4{0.f,0.f,0.f,0.f};
  float m_i[4], l_i[4];
  #pragma unroll
  for (int i = 0; i < 4; i++){ m_i[i] = -1e30f; l_i[i] = 0.f; }

  const int nt = qt + 1;
  for (int t = 0; t < nt; ++t){
    const int kv0 = t * 64;
    // stage K tile 64x128 -> Ks[r][c] stride 136  (16 x 16B segments per row)
    #pragma unroll
    for (int i = 0; i < 4; i++){
      int idx = i*256 + tid;
      int r = idx >> 4, cb = idx & 15;
      bf16x8 tmp = *(const bf16x8*)&Kg[(size_t)(b*SEQ + kv0 + r) * (NKVH*HDIM) + g*HDIM + cb*8];
      *(bf16x8*)&Ks[r*136 + cb*8] = tmp;
    }
    // stage Vt tile 128x64 -> Vs[d][kv] stride 72  (8 x 16B segments per row)
    #pragma unroll
    for (int i = 0; i < 4; i++){
      int idx = i*256 + tid;
      int d = idx >> 3, cb = idx & 7;
      bf16x8 tmp = *(const bf16x8*)&Vt[(size_t)((b*NKVH + g)*HDIM + d) * SEQ + kv0 + cb*8];
      *(bf16x8*)&Vs[d*72 + cb*8] = tmp;
    }
    __syncthreads();

    // S = Q K^T (scaled already): 4 col-frags x 4 k-chunks
    f32x4 sf[4];
    #pragma unroll
    for (int n = 0; n < 4; n++){
      f32x4 a = f32x4{0.f,0.f,0.f,0.f};
      #pragma unroll
      for (int c = 0; c < 4; c++){
        bf16x8 kf = *(const bf16x8*)&Ks[(n*16 + lr)*136 + c*32 + lk*8];
        a = __builtin_amdgcn_mfma_f32_16x16x32_bf16(qf[c], kf, a, 0, 0, 0);
      }
      sf[n] = a;
    }
    if (t == nt - 1){   // diagonal tile: causal mask
      #pragma unroll
      for (int n = 0; n < 4; n++)
        #pragma unroll
        for (int i = 0; i < 4; i++){
          int kvg = kv0 + n*16 + lr;
          int qg  = q0 + wid*16 + lk*4 + i;
          if (kvg > qg) sf[n][i] = -1e30f;
        }
    }
    // online softmax: rows live in 16-lane groups (col = lr)
    float rm[4];
    #pragma unroll
    for (int i = 0; i < 4; i++) rm[i] = fmaxf(fmaxf(sf[0][i], sf[1][i]), fmaxf(sf[2][i], sf[3][i]));
    #pragma unroll
    for (int off = 1; off < 16; off <<= 1)
      #pragma unroll
      for (int i = 0; i < 4; i++) rm[i] = fmaxf(rm[i], __shfl_xor(rm[i], off));

    float p[4][4], rs[4];
    #pragma unroll
    for (int i = 0; i < 4; i++){
      float mn = fmaxf(m_i[i], rm[i]);
      float cf = __expf(m_i[i] - mn);
      float s0 = 0.f;
      #pragma unroll
      for (int n = 0; n < 4; n++){ float pv = __expf(sf[n][i] - mn); p[n][i] = pv; s0 += pv; }
      rs[i] = s0; m_i[i] = mn; l_i[i] *= cf;
      #pragma unroll
      for (int f = 0; f < 8; f++) oacc[f][i] *= cf;
    }
    #pragma unroll
    for (int off = 1; off < 16; off <<= 1)
      #pragma unroll
      for (int i = 0; i < 4; i++) rs[i] += __shfl_xor(rs[i], off);
    #pragma unroll
    for (int i = 0; i < 4; i++) l_i[i] += rs[i];

    // P -> LDS bf16 (per-wave buffer, stride 72)
    #pragma unroll
    for (int n = 0; n < 4; n++)
      #pragma unroll
      for (int i = 0; i < 4; i++)
        Ps[wid][(lk*4 + i)*72 + n*16 + lr] = f2bf(p[n][i]);

    // O += P V
    #pragma unroll
    for (int kc = 0; kc < 2; kc++){
      bf16x8 pf = *(const bf16x8*)&Ps[wid][lr*72 + kc*32 + lk*8];
      #pragma unroll
      for (int f = 0; f < 8; f++){
        bf16x8 vf = *(const bf16x8*)&Vs[(f*16 + lr)*72 + kc*32 + lk*8];
        oacc[f] = __builtin_amdgcn_mfma_f32_16x16x32_bf16(pf, vf, oacc[f], 0, 0, 0);
      }
    }
    __syncthreads();
  }
  // epilogue: O[b][q][h*128 + d] bf16
  #pragma unroll
  for (int f = 0; f < 8; f++)
    #pragma unroll
    for (int i = 0; i < 4; i++){
      int qr = q0 + wid*16 + lk*4 + i;
      float v = oacc[f][i] / l_i[i];
      O[(size_t)(b*SEQ + qr) * (NHQ*HDIM) + h*HDIM + f*16 + lr] = f2bf(v);
    }
}

// ---------------- launch ----------------

extern "C" void kernel_launch(void* const* d_in, const int* in_sizes, int n_in,
                              void* d_out, int out_size, void* d_ws, size_t ws_size,
                              hipStream_t stream){
  const float* x    = (const float*)d_in[0];
  const float* cosb = (const float*)d_in[1];
  const float* sinb = (const float*)d_in[2];
  const float* wq   = (const float*)d_in[3];
  const float* wk   = (const float*)d_in[4];
  const float* wv   = (const float*)d_in[5];
  const float* wo   = (const float*)d_in[6];
  float* out = (float*)d_out;

  char* ws = (char*)d_ws;
  u16* XB  = (u16*)(ws);                      // 32 MB: x bf16; later reused as attention output O
  u16* WQT = (u16*)(ws + 33554432);           // 8 MB
  u16* WKT = (u16*)(ws + 41943040);           // 2 MB
  u16* WVT = (u16*)(ws + 44040192);           // 2 MB
  u16* WOT = (u16*)(ws + 46137344);           // 8 MB
  u16* Qb  = (u16*)(ws + 54525952);           // 32 MB
  u16* Kb  = (u16*)(ws + 88080384);           // 8 MB
  u16* Vb  = (u16*)(ws + 96468992);           // 8 MB
  u16* VT  = (u16*)(ws + 104857600);          // 8 MB   (end: 113246208)

  dim3 tb(32, 8);
  // x -> bf16
  cvt_f32_bf16<<<(BATCH*SEQ*HIDD/4 + 255)/256, 256, 0, stream>>>(x, XB, BATCH*SEQ*HIDD/4);
  // weights -> bf16 transposed [N][K]
  transpose_cvt_f32<<<dim3(HIDD/32, HIDD/32), tb, 0, stream>>>(wq, WQT, HIDD, NHQ*HDIM);
  transpose_cvt_f32<<<dim3((NKVH*HDIM)/32, HIDD/32), tb, 0, stream>>>(wk, WKT, HIDD, NKVH*HDIM);
  transpose_cvt_f32<<<dim3((NKVH*HDIM)/32, HIDD/32), tb, 0, stream>>>(wv, WVT, HIDD, NKVH*HDIM);
  transpose_cvt_f32<<<dim3(HIDD/32, HIDD/32), tb, 0, stream>>>(wo, WOT, NHQ*HDIM, HIDD);
  // projections
  gemm_bt<1><<<dim3((NHQ*HDIM)/128, BATCH*SEQ/128), 256, 0, stream>>>(XB, WQT, Qb, BATCH*SEQ, NHQ*HDIM, HIDD);
  gemm_bt<1><<<dim3((NKVH*HDIM)/128, BATCH*SEQ/128), 256, 0, stream>>>(XB, WKT, Kb, BATCH*SEQ, NKVH*HDIM, HIDD);
  gemm_bt<1><<<dim3((NKVH*HDIM)/128, BATCH*SEQ/128), 256, 0, stream>>>(XB, WVT, Vb, BATCH*SEQ, NKVH*HDIM, HIDD);
  // RoPE (Q gets the 1/sqrt(HD) fold)
  rope_kernel<<<(BATCH*SEQ*NHQ*HDIM/8)/256, 256, 0, stream>>>(Qb, cosb, sinb, NHQ*HDIM, 0.088388347648318447f, BATCH*SEQ*NHQ*HDIM/8);
  rope_kernel<<<(BATCH*SEQ*NKVH*HDIM/8)/256, 256, 0, stream>>>(Kb, cosb, sinb, NKVH*HDIM, 1.0f, BATCH*SEQ*NKVH*HDIM/8);
  // V -> [B][NKV][HD][S]
  transpose_v<<<dim3(HDIM/32, SEQ/32, BATCH*NKVH), tb, 0, stream>>>(Vb, VT);
  // attention (writes O into XB region — x no longer needed)
  attn_kernel<<<dim3(SEQ/64, NHQ, BATCH), 256, 0, stream>>>(Qb, Kb, VT, XB);
  // out projection (f32 out)
  gemm_bt<0><<<dim3(HIDD/128, BATCH*SEQ/128), 256, 0, stream>>>(XB, WOT, out, BATCH*SEQ, HIDD, NHQ*HDIM);
}

// Round 3
// 758.170 us; speedup vs baseline: 1.1177x; 1.1177x over previous
//
#include <hip/hip_runtime.h>

#define HIDD 2048
#define SEQ  2048
#define BATCH 4
#define NHQ  16
#define NKVH 4
#define HDIM 128
#define QKVN 3072   // 2048 Q + 512 K + 512 V

typedef unsigned short u16;
typedef unsigned int   u32;
using bf16x8 = __attribute__((ext_vector_type(8))) __bf16;
using u16x8  = __attribute__((ext_vector_type(8))) u16;
using u16x4  = __attribute__((ext_vector_type(4))) u16;
using f32x4  = __attribute__((ext_vector_type(4))) float;

__device__ __forceinline__ float bf2f(u16 v){ u32 u = ((u32)v) << 16; float f; __builtin_memcpy(&f, &u, 4); return f; }
__device__ __forceinline__ u16 f2bf(float f){ u32 u; __builtin_memcpy(&u, &f, 4); u += 0x7fffu + ((u >> 16) & 1u); return (u16)(u >> 16); }

__device__ __forceinline__ void gl_lds16(const void* g, void* l){
  __builtin_amdgcn_global_load_lds((const __attribute__((address_space(1))) void*)g,
                                   (__attribute__((address_space(3))) void*)l, 16, 0, 0);
}

// ---------------- prep kernels ----------------

__global__ void cvt_f32_bf16(const float* __restrict__ in, u16* __restrict__ out, int n4){
  int i = blockIdx.x * 256 + threadIdx.x;
  if (i >= n4) return;
  float4 v = ((const float4*)in)[i];
  u16x4 o; o[0] = f2bf(v.x); o[1] = f2bf(v.y); o[2] = f2bf(v.z); o[3] = f2bf(v.w);
  ((u16x4*)out)[i] = o;
}

// in: f32 [R][C] -> out: bf16 [C][R]  (out may point into a larger [*][R] buffer)
__global__ void transpose_cvt_f32(const float* __restrict__ in, u16* __restrict__ out, int R, int C){
  __shared__ float t[32][33];
  int c0 = blockIdx.x * 32, r0 = blockIdx.y * 32;
  int tx = threadIdx.x, ty = threadIdx.y;
  #pragma unroll
  for (int i = 0; i < 4; i++)
    t[ty + 8*i][tx] = in[(size_t)(r0 + ty + 8*i) * C + c0 + tx];
  __syncthreads();
  #pragma unroll
  for (int i = 0; i < 4; i++)
    out[(size_t)(c0 + ty + 8*i) * R + r0 + tx] = f2bf(t[tx][ty + 8*i]);
}

// V slice of QKV [B*S][ld] bf16 (cols voff..voff+511) -> Vt [B][NKV][HD][S] bf16
__global__ void transpose_v(const u16* __restrict__ V, u16* __restrict__ Vt, int ld, int voff){
  __shared__ u16 t[32][33];
  int bg = blockIdx.z;
  int b = bg >> 2, g = bg & 3;
  const u16* in = V + (size_t)b * SEQ * ld + voff + g * HDIM;
  u16* out = Vt + (size_t)bg * HDIM * SEQ;
  int c0 = blockIdx.x * 32, r0 = blockIdx.y * 32;   // c: d (0..127), r: s
  int tx = threadIdx.x, ty = threadIdx.y;
  #pragma unroll
  for (int i = 0; i < 4; i++)
    t[ty + 8*i][tx] = in[(size_t)(r0 + ty + 8*i) * ld + c0 + tx];
  __syncthreads();
  #pragma unroll
  for (int i = 0; i < 4; i++)
    out[(size_t)(c0 + ty + 8*i) * SEQ + r0 + tx] = t[tx][ty + 8*i];
}

// in-place RoPE on bf16 rows of a [rows][ld] buffer, covering ncol=2^ncl columns at X.
// cos/sin f32 [S][HD]; scale folded into output (Q: log2e/sqrt(HD)).
__global__ void rope_kernel(u16* __restrict__ X, int ld, int ncl,
                            const float* __restrict__ ct, const float* __restrict__ st,
                            float scale, int n8){
  int i = blockIdx.x * 256 + threadIdx.x;
  if (i >= n8) return;
  int e0 = i * 8;
  int row = e0 >> ncl;
  int col = e0 & ((1 << ncl) - 1);
  int pos = row & (SEQ - 1);
  int dd  = col & (HDIM - 1);
  u16* p = X + (size_t)row * ld + col;
  u16x8 v = *(const u16x8*)p;
  const float* cp = ct + (size_t)pos * HDIM + dd;
  const float* sp = st + (size_t)pos * HDIM + dd;
  float f[8];
  #pragma unroll
  for (int j = 0; j < 8; j++) f[j] = bf2f(v[j]);
  u16x8 o;
  #pragma unroll
  for (int j = 0; j < 8; j += 2){
    float c = cp[j], s = sp[j];        // cos/sin repeated in pairs
    float e = f[j], od = f[j+1];
    o[j]   = f2bf((e * c - od * s) * scale);
    o[j+1] = f2bf((od * c + e * s) * scale);
  }
  *(u16x8*)p = o;
}

// ---------------- GEMM: C[M][N] = A[M][K] * Bt[N][K]^T (bf16 in, f32 acc) ----------------
template<int OUT_BF16>
__global__ __launch_bounds__(256) void gemm_bt(const u16* __restrict__ A, const u16* __restrict__ Bt,
                                               void* __restrict__ Cv, int M, int N, int K){
  __shared__ __align__(16) u16 As[128*32];
  __shared__ __align__(16) u16 Bs[128*32];
  const int tid = threadIdx.x;
  const int wid = tid >> 6, lane = tid & 63;
  const int lr = lane & 15, lk = lane >> 4;
  const int m0 = blockIdx.y * 128, n0 = blockIdx.x * 128;
  const int wr = (wid >> 1) * 64, wc = (wid & 1) * 64;

  f32x4 acc[4][4];
  #pragma unroll
  for (int m = 0; m < 4; m++)
    #pragma unroll
    for (int n = 0; n < 4; n++) acc[m][n] = f32x4{0.f,0.f,0.f,0.f};

  const int srow = lane >> 2;
  const int swz  = ((lane & 3) * 8) ^ ((srow & 3) * 8);
  const u16* Ag = A  + (size_t)(m0 + wid*32 + srow) * K + swz;
  const u16* Bg = Bt + (size_t)(n0 + wid*32 + srow) * K + swz;
  u16* Asl = As + wid * 1024;
  u16* Bsl = Bs + wid * 1024;
  const int rsw = (lr & 3) * 8;

  for (int k0 = 0; k0 < K; k0 += 32){
    gl_lds16(Ag + k0,          Asl);
    gl_lds16(Ag + k0 + 16*K,   Asl + 512);
    gl_lds16(Bg + k0,          Bsl);
    gl_lds16(Bg + k0 + 16*K,   Bsl + 512);
    __syncthreads();
    bf16x8 a[4], b[4];
    #pragma unroll
    for (int m = 0; m < 4; m++) a[m] = *(const bf16x8*)&As[(wr + m*16 + lr)*32 + ((lk*8) ^ rsw)];
    #pragma unroll
    for (int n = 0; n < 4; n++) b[n] = *(const bf16x8*)&Bs[(wc + n*16 + lr)*32 + ((lk*8) ^ rsw)];
    #pragma unroll
    for (int m = 0; m < 4; m++)
      #pragma unroll
      for (int n = 0; n < 4; n++)
        acc[m][n] = __builtin_amdgcn_mfma_f32_16x16x32_bf16(a[m], b[n], acc[m][n], 0, 0, 0);
    __syncthreads();
  }
  #pragma unroll
  for (int m = 0; m < 4; m++)
    #pragma unroll
    for (int n = 0; n < 4; n++)
      #pragma unroll
      for (int i = 0; i < 4; i++){
        int gr = m0 + wr + m*16 + lk*4 + i;
        int gc = n0 + wc + n*16 + lr;
        float v = acc[m][n][i];
        if (OUT_BF16) ((u16*)Cv)[(size_t)gr * N + gc] = f2bf(v);
        else          ((float*)Cv)[(size_t)gr * N + gc] = v;
      }
}

// ---------------- flash attention ----------------
// grid: (S/64, NH, B), block 256 (4 waves x 16 q-rows). KV tile 64. LPT: qt = 31 - bx.
// Q pre-scaled by log2e/sqrt(HD). K/V double-buffered linear LDS, staged via
// global_load_lds w16 with inverse-XOR-swizzled source; reads XOR-swizzle (chunk ^= row&7).
__global__ __launch_bounds__(256) void attn_kernel(const u16* __restrict__ QKV, const u16* __restrict__ Vt,
                                                   u16* __restrict__ O){
  const int qt = (gridDim.x - 1) - blockIdx.x;      // LPT: heavy blocks first
  const int h = blockIdx.y, b = blockIdx.z;
  const int g = h >> 2;
  const int tid = threadIdx.x;
  const int wid = tid >> 6, lane = tid & 63;
  const int lr = lane & 15, lk = lane >> 4;
  const int q0 = qt * 64;

  __shared__ __align__(16) u16 Ks[2][64*128];       // linear, swizzled contents
  __shared__ __align__(16) u16 Vs[2][128*64];       // linear, swizzled contents
  __shared__ __align__(16) u16 Ps[4][16*72];

  // ---- Q fragments (row stride QKVN) ----
  bf16x8 qf[4];
  {
    const int qrow = q0 + wid*16 + lr;
    const u16* qp = QKV + (size_t)(b*SEQ + qrow) * QKVN + h*HDIM + lk*8;
    #pragma unroll
    for (int c = 0; c < 4; c++) qf[c] = *(const bf16x8*)(qp + c*32);
  }

  // ---- staging helpers (async, wave-uniform LDS dest, per-lane swizzled global src) ----
  const u16* Kbase = QKV + (size_t)b * SEQ * QKVN + HIDD + g*HDIM;  // K cols start at 2048
  const u16* Vbase = Vt + (size_t)(b*NKVH + g) * HDIM * SEQ;
  const int klr = lane >> 4, kj = lane & 15;        // K: 4 rows x 16 chunks per KB
  const int vlr = lane >> 3, vj = lane & 7;         // V: 8 rows x 8 chunks per KB

  #define STAGE(buf, t) do {                                                        \
    int kv0_ = (t) * 64;                                                            \
    _Pragma("unroll")                                                               \
    for (int iw = 0; iw < 4; iw++){                                                 \
      int kcb = wid*4 + iw;                                                         \
      int r   = kcb*4 + klr;                                                        \
      gl_lds16(Kbase + (size_t)(kv0_ + r) * QKVN + ((kj ^ (r & 7)) << 3),           \
               &Ks[buf][kcb << 9]);                                                 \
      int d   = kcb*8 + vlr;                                                        \
      gl_lds16(Vbase + (size_t)d * SEQ + kv0_ + ((vj ^ (d & 7)) << 3),              \
               &Vs[buf][kcb << 9]);                                                 \
    }                                                                               \
  } while (0)

  f32x4 oacc[8];
  #pragma unroll
  for (int f = 0; f < 8; f++) oacc[f] = f32x4{0.f,0.f,0.f,0.f};
  float m_i[4], l_i[4];
  #pragma unroll
  for (int i = 0; i < 4; i++){ m_i[i] = -1e30f; l_i[i] = 0.f; }

  const int nt = qt + 1;
  int cur = 0;
  STAGE(0, 0);
  for (int t = 0; t < nt; ++t){
    __syncthreads();                    // stage(cur) complete (vmcnt0 before barrier); prev reads done
    if (t + 1 < nt) STAGE(cur ^ 1, t + 1);   // fly during this tile's compute

    const int kv0 = t * 64;
    // S' = (Q*log2e/sqrt(d)) K^T
    f32x4 sf[4];
    #pragma unroll
    for (int n = 0; n < 4; n++){
      f32x4 a = f32x4{0.f,0.f,0.f,0.f};
      #pragma unroll
      for (int c = 0; c < 4; c++){
        bf16x8 kf = *(const bf16x8*)&Ks[cur][(n*16 + lr)*128 + (((c*4 + lk) ^ (lr & 7)) << 3)];
        a = __builtin_amdgcn_mfma_f32_16x16x32_bf16(qf[c], kf, a, 0, 0, 0);
      }
      sf[n] = a;
    }
    if (t == nt - 1){   // diagonal tile: causal mask
      #pragma unroll
      for (int n = 0; n < 4; n++)
        #pragma unroll
        for (int i = 0; i < 4; i++){
          int kvg = kv0 + n*16 + lr;
          int qg  = q0 + wid*16 + lk*4 + i;
          if (kvg > qg) sf[n][i] = -1e30f;
        }
    }
    // online softmax in exp2 domain; rows live in 16-lane groups
    float rm[4];
    #pragma unroll
    for (int i = 0; i < 4; i++) rm[i] = fmaxf(fmaxf(sf[0][i], sf[1][i]), fmaxf(sf[2][i], sf[3][i]));
    #pragma unroll
    for (int off = 1; off < 16; off <<= 1)
      #pragma unroll
      for (int i = 0; i < 4; i++) rm[i] = fmaxf(rm[i], __shfl_xor(rm[i], off));

    int defer = 1;
    #pragma unroll
    for (int i = 0; i < 4; i++) defer &= (rm[i] <= m_i[i] + 11.5f);   // ~8 nats in log2 domain

    float p[4][4], rs[4];
    if (__all(defer)){
      #pragma unroll
      for (int i = 0; i < 4; i++){
        float s0 = 0.f;
        #pragma unroll
        for (int n = 0; n < 4; n++){ float pv = exp2f(sf[n][i] - m_i[i]); p[n][i] = pv; s0 += pv; }
        rs[i] = s0;
      }
    } else {
      #pragma unroll
      for (int i = 0; i < 4; i++){
        float mn = fmaxf(m_i[i], rm[i]);
        float cf = exp2f(m_i[i] - mn);
        float s0 = 0.f;
        #pragma unroll
        for (int n = 0; n < 4; n++){ float pv = exp2f(sf[n][i] - mn); p[n][i] = pv; s0 += pv; }
        rs[i] = s0; m_i[i] = mn; l_i[i] *= cf;
        #pragma unroll
        for (int f = 0; f < 8; f++) oacc[f][i] *= cf;
      }
    }
    #pragma unroll
    for (int off = 1; off < 16; off <<= 1)
      #pragma unroll
      for (int i = 0; i < 4; i++) rs[i] += __shfl_xor(rs[i], off);
    #pragma unroll
    for (int i = 0; i < 4; i++) l_i[i] += rs[i];

    // P -> LDS bf16 (per-wave buffer, stride 72)
    #pragma unroll
    for (int n = 0; n < 4; n++)
      #pragma unroll
      for (int i = 0; i < 4; i++)
        Ps[wid][(lk*4 + i)*72 + n*16 + lr] = f2bf(p[n][i]);

    // O += P V
    #pragma unroll
    for (int kc = 0; kc < 2; kc++){
      bf16x8 pf = *(const bf16x8*)&Ps[wid][lr*72 + kc*32 + lk*8];
      #pragma unroll
      for (int f = 0; f < 8; f++){
        bf16x8 vf = *(const bf16x8*)&Vs[cur][(f*16 + lr)*64 + (((kc*4 + lk) ^ (lr & 7)) << 3)];
        oacc[f] = __builtin_amdgcn_mfma_f32_16x16x32_bf16(pf, vf, oacc[f], 0, 0, 0);
      }
    }
    cur ^= 1;
  }
  #undef STAGE
  // epilogue: O[b][q][h*128 + d] bf16
  #pragma unroll
  for (int f = 0; f < 8; f++)
    #pragma unroll
    for (int i = 0; i < 4; i++){
      int qr = q0 + wid*16 + lk*4 + i;
      float v = oacc[f][i] / l_i[i];
      O[(size_t)(b*SEQ + qr) * (NHQ*HDIM) + h*HDIM + f*16 + lr] = f2bf(v);
    }
}

// ---------------- launch ----------------

extern "C" void kernel_launch(void* const* d_in, const int* in_sizes, int n_in,
                              void* d_out, int out_size, void* d_ws, size_t ws_size,
                              hipStream_t stream){
  const float* x    = (const float*)d_in[0];
  const float* cosb = (const float*)d_in[1];
  const float* sinb = (const float*)d_in[2];
  const float* wq   = (const float*)d_in[3];
  const float* wk   = (const float*)d_in[4];
  const float* wv   = (const float*)d_in[5];
  const float* wo   = (const float*)d_in[6];
  float* out = (float*)d_out;

  char* ws = (char*)d_ws;
  u16* XB    = (u16*)(ws);                    // 32 MB: x bf16; later attention output O
  u16* WQKVT = (u16*)(ws + 33554432);         // 12.6 MB: [3072][2048] (Q rows 0..2047, K 2048..2559, V 2560..3071)
  u16* WOT   = (u16*)(ws + 46137344);         // 8 MB
  u16* QKV   = (u16*)(ws + 54525952);         // 50.3 MB: [8192][3072]
  u16* VT    = (u16*)(ws + 104857600);        // 8 MB   (end: 113246208)

  dim3 tb(32, 8);
  // x -> bf16
  cvt_f32_bf16<<<(BATCH*SEQ*HIDD/4 + 255)/256, 256, 0, stream>>>(x, XB, BATCH*SEQ*HIDD/4);
  // weights -> bf16 transposed, fused QKV weight [3072][2048]
  transpose_cvt_f32<<<dim3(HIDD/32, HIDD/32), tb, 0, stream>>>(wq, WQKVT, HIDD, NHQ*HDIM);
  transpose_cvt_f32<<<dim3((NKVH*HDIM)/32, HIDD/32), tb, 0, stream>>>(wk, WQKVT + (size_t)2048*2048, HIDD, NKVH*HDIM);
  transpose_cvt_f32<<<dim3((NKVH*HDIM)/32, HIDD/32), tb, 0, stream>>>(wv, WQKVT + (size_t)2560*2048, HIDD, NKVH*HDIM);
  transpose_cvt_f32<<<dim3(HIDD/32, HIDD/32), tb, 0, stream>>>(wo, WOT, NHQ*HDIM, HIDD);
  // fused QKV projection: [8192][3072]
  gemm_bt<1><<<dim3(QKVN/128, BATCH*SEQ/128), 256, 0, stream>>>(XB, WQKVT, QKV, BATCH*SEQ, QKVN, HIDD);
  // RoPE: Q cols (scale = log2e/sqrt(128)), K cols (scale 1)
  rope_kernel<<<(BATCH*SEQ*2048/8)/256, 256, 0, stream>>>(QKV, QKVN, 11, cosb, sinb, 0.12753165651003169f, BATCH*SEQ*2048/8);
  rope_kernel<<<(BATCH*SEQ*512/8)/256, 256, 0, stream>>>(QKV + HIDD, QKVN, 9, cosb, sinb, 1.0f, BATCH*SEQ*512/8);
  // V -> [B][NKV][HD][S]
  transpose_v<<<dim3(HDIM/32, SEQ/32, BATCH*NKVH), tb, 0, stream>>>(QKV, VT, QKVN, 2560);
  // attention (writes O into XB region)
  attn_kernel<<<dim3(SEQ/64, NHQ, BATCH), 256, 0, stream>>>(QKV, VT, XB);
  // out projection (f32 out)
  gemm_bt<0><<<dim3(HIDD/128, BATCH*SEQ/128), 256, 0, stream>>>(XB, WOT, out, BATCH*SEQ, HIDD, NHQ*HDIM);
}